// Round 2
// baseline (175.460 us; speedup 1.0000x reference)
//
#include <hip/hip_runtime.h>

// MHSA: B=2, S=2048, D=1024, H=16, hd=64. fp32 in/out, bf16 MFMA internally.
// cvt(all) -> gemm_qkv(Q*SC,K + V^T split, LDS dbuf) -> flash attn (S^T, 8-wave: 4qg x 2kg,
//             cross-tile pipelined: PV lags S by one tile) -> gemm_out(+bias, LDS dbuf)

typedef __attribute__((ext_vector_type(8))) short short8;
typedef __attribute__((ext_vector_type(4))) float f32x4;
typedef unsigned short ushort_t;
typedef unsigned int uint32;

#define AS1 __attribute__((address_space(1)))
#define AS3 __attribute__((address_space(3)))

__device__ __forceinline__ void gload_lds16(const void* gp, void* lp) {
    __builtin_amdgcn_global_load_lds((const AS1 void*)gp, (AS3 void*)lp, 16, 0, 0);
}

#if __has_builtin(__builtin_amdgcn_exp2f)
#define EXP2F(x) __builtin_amdgcn_exp2f(x)
#else
#define EXP2F(x) exp2f(x)
#endif

__device__ __forceinline__ uint32 rhu(float f) { return __float_as_uint(f) + 0x8000u; }
#if __has_builtin(__builtin_amdgcn_perm)
__device__ __forceinline__ uint32 pk2bf(float a, float b) {
    return __builtin_amdgcn_perm(rhu(b), rhu(a), 0x07060302u);
}
#else
__device__ __forceinline__ uint32 pk2bf(float a, float b) {
    return (rhu(a) >> 16) | (rhu(b) & 0xffff0000u);
}
#endif
__device__ __forceinline__ ushort_t f2bf(float f) { return (ushort_t)(rhu(f) >> 16); }

// ---------------- fused fp32 -> bf16 convert ----------------
__global__ void cvt_all(const float* __restrict__ x, ushort_t* __restrict__ xb,
                        const float* __restrict__ wq, ushort_t* __restrict__ wqb,
                        const float* __restrict__ wo, ushort_t* __restrict__ wob) {
    int blk = blockIdx.x;
    const float* in; ushort_t* out;
    if (blk < 4096)      { in = x;  out = xb;  }
    else if (blk < 7168) { in = wq; out = wqb; blk -= 4096; }
    else                 { in = wo; out = wob; blk -= 7168; }
    const int i = (blk * 256 + threadIdx.x) * 4;
    const float4 v = *(const float4*)(in + i);
    uint2 pk;
    pk.x = pk2bf(v.x, v.y);
    pk.y = pk2bf(v.z, v.w);
    *(uint2*)(out + i) = pk;
}

// ---------------- GEMM1: qkv = x·Wqkv^T, 128x128 tile, BK=32, dbuf ----------------
__global__ __launch_bounds__(256, 2)
void gemm_qkv(const ushort_t* __restrict__ A, const ushort_t* __restrict__ B,
              ushort_t* __restrict__ Cb, ushort_t* __restrict__ vT,
              int M, int N, int K, int ldc, float qScale) {
    __shared__ ushort_t lA[2][128 * 32];
    __shared__ ushort_t lB[2][128 * 32];
    const int tid = threadIdx.x;
    const int wave = tid >> 6, lane = tid & 63;
    const int quad = lane >> 4, l16 = lane & 15;
    const int wr = wave >> 1, wc = wave & 1;
    const int mBase = blockIdx.y * 128, nBase = blockIdx.x * 128;

    f32x4 acc[4][4];
#pragma unroll
    for (int i = 0; i < 4; i++)
#pragma unroll
        for (int j = 0; j < 4; j++) acc[i][j] = (f32x4){0.f, 0.f, 0.f, 0.f};

    const int ar = tid >> 2;
    const int ac = (((tid & 3) ^ ((ar >> 1) & 3)) * 8);
    const int rsw = ((l16 >> 1) & 3);

    const ushort_t* aptr = A + (size_t)(mBase + ar) * K + ac;
    const ushort_t* bptr = B + (size_t)(nBase + ar) * K + ac;

#define G1_STAGE(buf, k0)                                                            \
    {                                                                                \
        _Pragma("unroll") for (int c = 0; c < 2; c++) {                              \
            gload_lds16(aptr + (size_t)(c * 64) * K + (k0), lA[buf] + c * 2048 + wave * 512); \
            gload_lds16(bptr + (size_t)(c * 64) * K + (k0), lB[buf] + c * 2048 + wave * 512); \
        }                                                                            \
    }

    G1_STAGE(0, 0);
    for (int k0 = 0; k0 < K; k0 += 32) {
        const int cur = (k0 >> 5) & 1;
        __syncthreads();
        if (k0 + 32 < K) G1_STAGE(cur ^ 1, k0 + 32);

        short8 af[4], bf[4];
#pragma unroll
        for (int i = 0; i < 4; i++)
            af[i] = *(const short8*)(lA[cur] + (wr * 64 + i * 16 + l16) * 32 + ((quad ^ rsw) * 8));
#pragma unroll
        for (int j = 0; j < 4; j++)
            bf[j] = *(const short8*)(lB[cur] + (wc * 64 + j * 16 + l16) * 32 + ((quad ^ rsw) * 8));
#pragma unroll
        for (int i = 0; i < 4; i++)
#pragma unroll
            for (int j = 0; j < 4; j++)
                acc[i][j] = __builtin_amdgcn_mfma_f32_16x16x32_bf16(af[i], bf[j], acc[i][j], 0, 0, 0);
    }

    if (nBase >= 2048) {
#pragma unroll
        for (int i = 0; i < 4; i++)
#pragma unroll
            for (int j = 0; j < 4; j++) {
                const int row0 = mBase + wr * 64 + i * 16 + quad * 4;
                const int col = nBase + wc * 64 + j * 16 + l16 - 2048;
                const int b = row0 >> 11, s0 = row0 & 2047;
                uint2 pk;
                pk.x = pk2bf(acc[i][j][0], acc[i][j][1]);
                pk.y = pk2bf(acc[i][j][2], acc[i][j][3]);
                *(uint2*)(vT + ((size_t)(b * 16) * 64 + col) * 2048 + s0) = pk;
            }
        return;
    }
    const float cs = (nBase < 1024) ? qScale : 1.0f;
#pragma unroll
    for (int i = 0; i < 4; i++)
#pragma unroll
        for (int j = 0; j < 4; j++)
#pragma unroll
            for (int r = 0; r < 4; r++) {
                const int row = mBase + wr * 64 + i * 16 + quad * 4 + r;
                const int col = nBase + wc * 64 + j * 16 + l16;
                Cb[(size_t)row * ldc + col] = f2bf(acc[i][j][r] * cs);
            }
}

// ---------------- GEMM2: out = o·Wout^T + bias, 64x128 tile, BK=64, dbuf ----------------
__global__ __launch_bounds__(256, 2)
void gemm_out(const ushort_t* __restrict__ A, const ushort_t* __restrict__ B,
              float* __restrict__ Cf, const float* __restrict__ bias,
              int M, int N, int K) {
    __shared__ ushort_t lA[2][64 * 64];
    __shared__ ushort_t lB[2][128 * 64];
    const int tid = threadIdx.x;
    const int wave = tid >> 6, lane = tid & 63;
    const int quad = lane >> 4, l16 = lane & 15;
    const int mBase = blockIdx.y * 64, nBase = blockIdx.x * 128;

    f32x4 acc[4][2];
#pragma unroll
    for (int i = 0; i < 4; i++)
#pragma unroll
        for (int j = 0; j < 2; j++) acc[i][j] = (f32x4){0.f, 0.f, 0.f, 0.f};

    const int sr = tid >> 3;
    const int sc = ((tid & 7) ^ (sr & 7)) * 8;
    const int swz = l16 & 7;

    const ushort_t* aptr = A + (size_t)(mBase + sr) * K + sc;
    const ushort_t* bptr = B + (size_t)(nBase + sr) * K + sc;

#define G2_STAGE(buf, k0)                                                              \
    {                                                                                  \
        _Pragma("unroll") for (int c = 0; c < 2; c++)                                  \
            gload_lds16(aptr + (size_t)(c * 32) * K + (k0), lA[buf] + c * 2048 + wave * 512); \
        _Pragma("unroll") for (int c = 0; c < 4; c++)                                  \
            gload_lds16(bptr + (size_t)(c * 32) * K + (k0), lB[buf] + c * 2048 + wave * 512); \
    }

    G2_STAGE(0, 0);
    for (int k0 = 0; k0 < K; k0 += 64) {
        const int cur = (k0 >> 6) & 1;
        __syncthreads();
        if (k0 + 64 < K) G2_STAGE(cur ^ 1, k0 + 64);

#pragma unroll
        for (int ks = 0; ks < 2; ks++) {
            short8 af[4], bf[2];
#pragma unroll
            for (int i = 0; i < 4; i++)
                af[i] = *(const short8*)(lA[cur] + (i * 16 + l16) * 64 + (((ks * 4 + quad) ^ swz) * 8));
#pragma unroll
            for (int j = 0; j < 2; j++)
                bf[j] = *(const short8*)(lB[cur] + (wave * 32 + j * 16 + l16) * 64 + (((ks * 4 + quad) ^ swz) * 8));
#pragma unroll
            for (int i = 0; i < 4; i++)
#pragma unroll
                for (int j = 0; j < 2; j++)
                    acc[i][j] = __builtin_amdgcn_mfma_f32_16x16x32_bf16(af[i], bf[j], acc[i][j], 0, 0, 0);
        }
    }

#pragma unroll
    for (int i = 0; i < 4; i++)
#pragma unroll
        for (int j = 0; j < 2; j++)
#pragma unroll
            for (int r = 0; r < 4; r++) {
                const int row = mBase + i * 16 + quad * 4 + r;
                const int col = nBase + wave * 32 + j * 16 + l16;
                Cf[(size_t)row * N + col] = acc[i][j][r] + bias[col];
            }
}

// ---------------- fused flash attention: 8 waves = 4 qg x 2 kg, PV lags S by one tile ----
// 512 thr = 8 waves, Bq=128: wave owns 32 q x 32 keys of each 64-key tile.
// Cross-tile pipeline: iter kt does S-MFMA(kt) then PV-MFMA(kt-1) from lP written last iter,
// then exp2(kt)->lP. Breaks the serial S->exp2->lPwrite->lPread->PV chain (was ~60% of iter).
// K dbuf (2x8KB), V 3-buf (3x8KB: tile kt-1 stays live while kt+1 stages; (kt+1)%3 != (kt-1)%3),
// lP single-buffered per-wave (read-P(kt-1)-then-write-P(kt), same-wave DS ops are in-order).
// smem ushort: [0,8192) K dbuf | [8192,20480) V 3-buf | [20480,30720) lP 8x(32x40)
// (lP region doubles as Q staging pre-loop; smem as f32 scratch post-loop). 60KB -> 2 blk/CU.
__global__ __launch_bounds__(512, 4)
void attn_flash(const ushort_t* __restrict__ qk, const ushort_t* __restrict__ vT,
                ushort_t* __restrict__ o) {
    __shared__ ushort_t smem[30720];

    const int tid = threadIdx.x;
    const int wave = tid >> 6, lane = tid & 63;
    const int quad = lane >> 4, l16 = lane & 15;
    const int qg = wave & 3, kg = wave >> 2;
    const int bh = blockIdx.y, b = bh >> 4, h = bh & 15;
    const size_t rowBase = (size_t)b * 2048;
    const int qCol = h * 64, kCol = 1024 + h * 64;
    const int qRow0 = blockIdx.x * 128;
    const int swz = l16 & 7;

    ushort_t* lP = smem + 20480 + wave * 1280;  // [32 q][32 k] stride 40 (2-way max)

    // staging geometry: 64 rows x 8 chunks per pass (512 thr = one full 64x64 tile), XOR swizzle
    const int sr = tid >> 3;                       // 0..63
    const int sc = ((tid & 7) ^ (sr & 7)) * 8;

    // ---- stage Q 128x64 (pre-scaled by SC) into lP region, pull B-frags ----
#pragma unroll
    for (int cc = 0; cc < 2; cc++)
        gload_lds16(qk + (rowBase + qRow0 + cc * 64 + sr) * 2048 + qCol + sc,
                    smem + 20480 + cc * 4096 + wave * 512);
    __syncthreads();
    short8 qf[2][2];  // [qt][ks]: q = qg*32 + qt*16 + l16
#pragma unroll
    for (int qt = 0; qt < 2; qt++)
#pragma unroll
        for (int ks = 0; ks < 2; ks++)
            qf[qt][ks] = *(const short8*)(smem + 20480 + (qg * 32 + qt * 16 + l16) * 64 +
                                          (((ks * 4 + quad) ^ swz) * 8));
    // Q-frag reads (all waves) complete before iter-0's lP writes: first loop barrier
    // waits lgkmcnt(0) per wave before s_barrier.

    short8 onesA;
#pragma unroll
    for (int i = 0; i < 8; i++) onesA[i] = (short)0x3F80;

    f32x4 oacc[4][2];  // [dt][qt]
    f32x4 lacc[2];     // [qt], entries replicate l
#pragma unroll
    for (int qt = 0; qt < 2; qt++) {
        lacc[qt] = (f32x4){0.f, 0.f, 0.f, 0.f};
#pragma unroll
        for (int dt = 0; dt < 4; dt++) oacc[dt][qt] = (f32x4){0.f, 0.f, 0.f, 0.f};
    }

    const ushort_t* kptr = qk + (rowBase + sr) * 2048 + kCol + sc;
    const ushort_t* vptr = vT + ((size_t)bh * 64 + sr) * 2048 + sc;

    f32x4 sacc[2][2];  // [mh][qt]

#define AT_STAGE(kbi, vbi, kt)                                                         \
    {                                                                                  \
        gload_lds16(kptr + (size_t)((kt) * 64) * 2048, smem + (kbi) * 4096 + wave * 512); \
        gload_lds16(vptr + (kt) * 64, smem + 8192 + (vbi) * 4096 + wave * 512);        \
    }

    // S^T = K·Q^T on 32 keys x 32 q: 4 reads feed 8 MFMA
#define S_BLOCK(cur)                                                                   \
    {                                                                                  \
        const ushort_t* lK = smem + (cur) * 4096;                                      \
        _Pragma("unroll") for (int mh = 0; mh < 2; mh++) {                             \
            const int krow = kg * 32 + mh * 16 + l16;                                  \
            const short8 k0 = *(const short8*)(lK + krow * 64 + ((quad ^ swz) * 8));   \
            const short8 k1 = *(const short8*)(lK + krow * 64 + (((4 + quad) ^ swz) * 8)); \
            __builtin_amdgcn_s_setprio(1);                                             \
            _Pragma("unroll") for (int qt = 0; qt < 2; qt++) {                         \
                f32x4 t = (f32x4){0.f, 0.f, 0.f, 0.f};                                 \
                t = __builtin_amdgcn_mfma_f32_16x16x32_bf16(k0, qf[qt][0], t, 0, 0, 0); \
                t = __builtin_amdgcn_mfma_f32_16x16x32_bf16(k1, qf[qt][1], t, 0, 0, 0); \
                sacc[mh][qt] = t;                                                      \
            }                                                                          \
            __builtin_amdgcn_s_setprio(0);                                             \
        }                                                                              \
    }

    // P = exp2(S^T) -> per-wave lP
#define EXP_BLOCK()                                                                    \
    _Pragma("unroll") for (int qt = 0; qt < 2; qt++)                                   \
        _Pragma("unroll") for (int mh = 0; mh < 2; mh++) {                             \
            const f32x4 s = sacc[mh][qt];                                              \
            uint2 pk;                                                                  \
            pk.x = pk2bf(EXP2F(s[0]), EXP2F(s[1]));                                    \
            pk.y = pk2bf(EXP2F(s[2]), EXP2F(s[3]));                                    \
            *(uint2*)(&lP[(qt * 16 + l16) * 40 + mh * 16 + quad * 4]) = pk;            \
        }

    // P·V (+ones·P for l) for the LAGGED tile: reads P written last iteration
#define PV_BLOCK(vbi)                                                                  \
    {                                                                                  \
        const ushort_t* lV = smem + 8192 + (vbi) * 4096;                               \
        short8 pf[2];                                                                  \
        _Pragma("unroll") for (int qt = 0; qt < 2; qt++) {                             \
            pf[qt] = *(const short8*)(&lP[(qt * 16 + l16) * 40 + quad * 8]);           \
            lacc[qt] = __builtin_amdgcn_mfma_f32_16x16x32_bf16(onesA, pf[qt], lacc[qt], 0, 0, 0); \
        }                                                                              \
        __builtin_amdgcn_s_setprio(1);                                                 \
        _Pragma("unroll") for (int dt = 0; dt < 4; dt++) {                             \
            const short8 vf = *(const short8*)(lV + (dt * 16 + l16) * 64 +             \
                                               (((kg * 4 + quad) ^ swz) * 8));         \
            _Pragma("unroll") for (int qt = 0; qt < 2; qt++)                           \
                oacc[dt][qt] = __builtin_amdgcn_mfma_f32_16x16x32_bf16(vf, pf[qt], oacc[dt][qt], 0, 0, 0); \
        }                                                                              \
        __builtin_amdgcn_s_setprio(0);                                                 \
    }

    AT_STAGE(0, 0, 0);

    // iter 0 (peeled): no PV yet
    __syncthreads();
    AT_STAGE(1, 1, 1);
    S_BLOCK(0);
    EXP_BLOCK();

    // main loop kt = 1..30: vbuf[t%3] holds tile t
    int vs = 2;  // (kt+1)%3
    int vp = 0;  // (kt-1)%3
    for (int kt = 1; kt <= 30; ++kt) {
        __syncthreads();  // tile kt staged; lagged-P writes (prev iter) drained per wave
        AT_STAGE((kt + 1) & 1, vs, kt + 1);
        S_BLOCK(kt & 1);
        PV_BLOCK(vp);   // tile kt-1 (reads lP before EXP_BLOCK overwrites it; same-wave order)
        EXP_BLOCK();
        vs = (vs == 2) ? 0 : vs + 1;
        vp = (vp == 2) ? 0 : vp + 1;
    }

    // iter 31 (peeled): no stage
    __syncthreads();
    S_BLOCK(1);
    PV_BLOCK(0);  // tile 30 (30%3 == 0)
    EXP_BLOCK();
    PV_BLOCK(1);  // tile 31 (31%3 == 1), P written just above (same-wave DS order)

    // ---- epilogue: combine the two key-halves through LDS, write O ----
    __syncthreads();  // all waves done with smem tiles
    float* red = (float*)smem;  // [0,8192) oacc f32, [8192,8320) l
    if (kg == 1) {
#pragma unroll
        for (int qt = 0; qt < 2; qt++) {
            if (quad == 0) red[8192 + qg * 32 + qt * 16 + l16] = lacc[qt][0];
#pragma unroll
            for (int dt = 0; dt < 4; dt++)
                *(f32x4*)(red + (((qg * 4 + dt) * 2 + qt) * 64 + lane) * 4) = oacc[dt][qt];
        }
    }
    __syncthreads();
    if (kg == 0) {
        float linv[2];
#pragma unroll
        for (int qt = 0; qt < 2; qt++)
            linv[qt] = 1.0f / (lacc[qt][0] + red[8192 + qg * 32 + qt * 16 + l16]);
#pragma unroll
        for (int qt = 0; qt < 2; qt++) {
            const size_t row = rowBase + qRow0 + qg * 32 + qt * 16 + l16;
#pragma unroll
            for (int dt = 0; dt < 4; dt++) {
                const f32x4 r = *(const f32x4*)(red + (((qg * 4 + dt) * 2 + qt) * 64 + lane) * 4);
                uint2 pk;
                pk.x = pk2bf((oacc[dt][qt][0] + r[0]) * linv[qt],
                             (oacc[dt][qt][1] + r[1]) * linv[qt]);
                pk.y = pk2bf((oacc[dt][qt][2] + r[2]) * linv[qt],
                             (oacc[dt][qt][3] + r[3]) * linv[qt]);
                *(uint2*)(o + row * 1024 + h * 64 + dt * 16 + quad * 4) = pk;
            }
        }
    }
}

extern "C" void kernel_launch(void* const* d_in, const int* in_sizes, int n_in,
                              void* d_out, int out_size, void* d_ws, size_t ws_size,
                              hipStream_t stream) {
    const float* x    = (const float*)d_in[0];
    const float* Wqkv = (const float*)d_in[1];
    const float* Wout = (const float*)d_in[2];
    const float* bout = (const float*)d_in[3];
    float* out = (float*)d_out;

    ushort_t* xb    = (ushort_t*)d_ws;                    // 4096*1024
    ushort_t* wqkvb = xb + (size_t)4096 * 1024;           // 3072*1024
    ushort_t* woutb = wqkvb + (size_t)3072 * 1024;        // 1024*1024
    ushort_t* qkb   = woutb + (size_t)1024 * 1024;        // 4096*2048 (Q*SC, K)
    ushort_t* vTb   = qkb + (size_t)4096 * 2048;          // 32*64*2048 (V^T)
    ushort_t* ob    = xb;                                 // alias: x dead after GEMM1

    const float SC = 0.125f * 1.44269504089f;  // SCALE * log2(e)

    cvt_all<<<8192, 256, 0, stream>>>(x, xb, Wqkv, wqkvb, Wout, woutb);
    gemm_qkv<<<dim3(24, 32), 256, 0, stream>>>(xb, wqkvb, qkb, vTb, 4096, 3072, 1024, 2048, SC);
    attn_flash<<<dim3(16, 32), 512, 0, stream>>>(qkb, vTb, ob);
    gemm_out<<<dim3(8, 64), 256, 0, stream>>>(ob, woutb, out, bout, 4096, 1024, 1024);
}

// Round 4
// 172.774 us; speedup vs baseline: 1.0155x; 1.0155x over previous
//
#include <hip/hip_runtime.h>

// MHSA: B=2, S=2048, D=1024, H=16, hd=64. fp32 in/out, bf16 MFMA internally.
// cvt(all) -> gemm_qkv(Q*SC,K + V^T split, LDS dbuf) -> flash attn (S^T, 8-wave: 4qg x 2kg,
//             PV lags S by one tile, P in registers via permlane swaps, XCD-local grid)
//          -> gemm_out(+bias, LDS dbuf)

typedef __attribute__((ext_vector_type(8))) short short8;
typedef __attribute__((ext_vector_type(4))) float f32x4;
typedef __attribute__((ext_vector_type(2))) unsigned int uint32x2;
typedef unsigned short ushort_t;
typedef unsigned int uint32;

#define AS1 __attribute__((address_space(1)))
#define AS3 __attribute__((address_space(3)))

__device__ __forceinline__ void gload_lds16(const void* gp, void* lp) {
    __builtin_amdgcn_global_load_lds((const AS1 void*)gp, (AS3 void*)lp, 16, 0, 0);
}

#if __has_builtin(__builtin_amdgcn_exp2f)
#define EXP2F(x) __builtin_amdgcn_exp2f(x)
#else
#define EXP2F(x) exp2f(x)
#endif

__device__ __forceinline__ uint32 rhu(float f) { return __float_as_uint(f) + 0x8000u; }
#if __has_builtin(__builtin_amdgcn_perm)
__device__ __forceinline__ uint32 pk2bf(float a, float b) {
    return __builtin_amdgcn_perm(rhu(b), rhu(a), 0x07060302u);
}
#else
__device__ __forceinline__ uint32 pk2bf(float a, float b) {
    return (rhu(a) >> 16) | (rhu(b) & 0xffff0000u);
}
#endif
__device__ __forceinline__ ushort_t f2bf(float f) { return (ushort_t)(rhu(f) >> 16); }

// gfx950 cross-lane row swaps (VALU, no LDS). plane32: vdst lanes32-63 <-> vsrc lanes0-31.
// plane16: vdst odd 16-rows <-> vsrc even 16-rows. Builtins preferred (correct encoding);
// inline-asm fallback.
#if __has_builtin(__builtin_amdgcn_permlane32_swap)
__device__ __forceinline__ void plane32(uint32& a, uint32& b) {
    uint32x2 r = __builtin_amdgcn_permlane32_swap(a, b, false, false);
    a = r[0]; b = r[1];
}
#else
__device__ __forceinline__ void plane32(uint32& a, uint32& b) {
    asm("v_permlane32_swap_b32 %0, %1" : "+v"(a), "+v"(b));
}
#endif
#if __has_builtin(__builtin_amdgcn_permlane16_swap)
__device__ __forceinline__ void plane16(uint32& a, uint32& b) {
    uint32x2 r = __builtin_amdgcn_permlane16_swap(a, b, false, false);
    a = r[0]; b = r[1];
}
#else
__device__ __forceinline__ void plane16(uint32& a, uint32& b) {
    asm("v_permlane16_swap_b32 %0, %1" : "+v"(a), "+v"(b));
}
#endif

// ---------------- fused fp32 -> bf16 convert ----------------
__global__ void cvt_all(const float* __restrict__ x, ushort_t* __restrict__ xb,
                        const float* __restrict__ wq, ushort_t* __restrict__ wqb,
                        const float* __restrict__ wo, ushort_t* __restrict__ wob) {
    int blk = blockIdx.x;
    const float* in; ushort_t* out;
    if (blk < 4096)      { in = x;  out = xb;  }
    else if (blk < 7168) { in = wq; out = wqb; blk -= 4096; }
    else                 { in = wo; out = wob; blk -= 7168; }
    const int i = (blk * 256 + threadIdx.x) * 4;
    const float4 v = *(const float4*)(in + i);
    uint2 pk;
    pk.x = pk2bf(v.x, v.y);
    pk.y = pk2bf(v.z, v.w);
    *(uint2*)(out + i) = pk;
}

// ---------------- GEMM1: qkv = x·Wqkv^T, 128x128 tile, BK=32, dbuf ----------------
__global__ __launch_bounds__(256, 2)
void gemm_qkv(const ushort_t* __restrict__ A, const ushort_t* __restrict__ B,
              ushort_t* __restrict__ Cb, ushort_t* __restrict__ vT,
              int M, int N, int K, int ldc, float qScale) {
    __shared__ ushort_t lA[2][128 * 32];
    __shared__ ushort_t lB[2][128 * 32];
    const int tid = threadIdx.x;
    const int wave = tid >> 6, lane = tid & 63;
    const int quad = lane >> 4, l16 = lane & 15;
    const int wr = wave >> 1, wc = wave & 1;
    const int mBase = blockIdx.y * 128, nBase = blockIdx.x * 128;

    f32x4 acc[4][4];
#pragma unroll
    for (int i = 0; i < 4; i++)
#pragma unroll
        for (int j = 0; j < 4; j++) acc[i][j] = (f32x4){0.f, 0.f, 0.f, 0.f};

    const int ar = tid >> 2;
    const int ac = (((tid & 3) ^ ((ar >> 1) & 3)) * 8);
    const int rsw = ((l16 >> 1) & 3);

    const ushort_t* aptr = A + (size_t)(mBase + ar) * K + ac;
    const ushort_t* bptr = B + (size_t)(nBase + ar) * K + ac;

#define G1_STAGE(buf, k0)                                                            \
    {                                                                                \
        _Pragma("unroll") for (int c = 0; c < 2; c++) {                              \
            gload_lds16(aptr + (size_t)(c * 64) * K + (k0), lA[buf] + c * 2048 + wave * 512); \
            gload_lds16(bptr + (size_t)(c * 64) * K + (k0), lB[buf] + c * 2048 + wave * 512); \
        }                                                                            \
    }

    G1_STAGE(0, 0);
    for (int k0 = 0; k0 < K; k0 += 32) {
        const int cur = (k0 >> 5) & 1;
        __syncthreads();
        if (k0 + 32 < K) G1_STAGE(cur ^ 1, k0 + 32);

        short8 af[4], bf[4];
#pragma unroll
        for (int i = 0; i < 4; i++)
            af[i] = *(const short8*)(lA[cur] + (wr * 64 + i * 16 + l16) * 32 + ((quad ^ rsw) * 8));
#pragma unroll
        for (int j = 0; j < 4; j++)
            bf[j] = *(const short8*)(lB[cur] + (wc * 64 + j * 16 + l16) * 32 + ((quad ^ rsw) * 8));
#pragma unroll
        for (int i = 0; i < 4; i++)
#pragma unroll
            for (int j = 0; j < 4; j++)
                acc[i][j] = __builtin_amdgcn_mfma_f32_16x16x32_bf16(af[i], bf[j], acc[i][j], 0, 0, 0);
    }

    if (nBase >= 2048) {
#pragma unroll
        for (int i = 0; i < 4; i++)
#pragma unroll
            for (int j = 0; j < 4; j++) {
                const int row0 = mBase + wr * 64 + i * 16 + quad * 4;
                const int col = nBase + wc * 64 + j * 16 + l16 - 2048;
                const int b = row0 >> 11, s0 = row0 & 2047;
                uint2 pk;
                pk.x = pk2bf(acc[i][j][0], acc[i][j][1]);
                pk.y = pk2bf(acc[i][j][2], acc[i][j][3]);
                *(uint2*)(vT + ((size_t)(b * 16) * 64 + col) * 2048 + s0) = pk;
            }
        return;
    }
    const float cs = (nBase < 1024) ? qScale : 1.0f;
#pragma unroll
    for (int i = 0; i < 4; i++)
#pragma unroll
        for (int j = 0; j < 4; j++)
#pragma unroll
            for (int r = 0; r < 4; r++) {
                const int row = mBase + wr * 64 + i * 16 + quad * 4 + r;
                const int col = nBase + wc * 64 + j * 16 + l16;
                Cb[(size_t)row * ldc + col] = f2bf(acc[i][j][r] * cs);
            }
}

// ---------------- GEMM2: out = o·Wout^T + bias, 64x128 tile, BK=64, dbuf ----------------
__global__ __launch_bounds__(256, 2)
void gemm_out(const ushort_t* __restrict__ A, const ushort_t* __restrict__ B,
              float* __restrict__ Cf, const float* __restrict__ bias,
              int M, int N, int K) {
    __shared__ ushort_t lA[2][64 * 64];
    __shared__ ushort_t lB[2][128 * 64];
    const int tid = threadIdx.x;
    const int wave = tid >> 6, lane = tid & 63;
    const int quad = lane >> 4, l16 = lane & 15;
    const int mBase = blockIdx.y * 64, nBase = blockIdx.x * 128;

    f32x4 acc[4][2];
#pragma unroll
    for (int i = 0; i < 4; i++)
#pragma unroll
        for (int j = 0; j < 2; j++) acc[i][j] = (f32x4){0.f, 0.f, 0.f, 0.f};

    const int sr = tid >> 3;
    const int sc = ((tid & 7) ^ (sr & 7)) * 8;
    const int swz = l16 & 7;

    const ushort_t* aptr = A + (size_t)(mBase + sr) * K + sc;
    const ushort_t* bptr = B + (size_t)(nBase + sr) * K + sc;

#define G2_STAGE(buf, k0)                                                              \
    {                                                                                  \
        _Pragma("unroll") for (int c = 0; c < 2; c++)                                  \
            gload_lds16(aptr + (size_t)(c * 32) * K + (k0), lA[buf] + c * 2048 + wave * 512); \
        _Pragma("unroll") for (int c = 0; c < 4; c++)                                  \
            gload_lds16(bptr + (size_t)(c * 32) * K + (k0), lB[buf] + c * 2048 + wave * 512); \
    }

    G2_STAGE(0, 0);
    for (int k0 = 0; k0 < K; k0 += 64) {
        const int cur = (k0 >> 6) & 1;
        __syncthreads();
        if (k0 + 64 < K) G2_STAGE(cur ^ 1, k0 + 64);

#pragma unroll
        for (int ks = 0; ks < 2; ks++) {
            short8 af[4], bf[2];
#pragma unroll
            for (int i = 0; i < 4; i++)
                af[i] = *(const short8*)(lA[cur] + (i * 16 + l16) * 64 + (((ks * 4 + quad) ^ swz) * 8));
#pragma unroll
            for (int j = 0; j < 2; j++)
                bf[j] = *(const short8*)(lB[cur] + (wave * 32 + j * 16 + l16) * 64 + (((ks * 4 + quad) ^ swz) * 8));
#pragma unroll
            for (int i = 0; i < 4; i++)
#pragma unroll
                for (int j = 0; j < 2; j++)
                    acc[i][j] = __builtin_amdgcn_mfma_f32_16x16x32_bf16(af[i], bf[j], acc[i][j], 0, 0, 0);
        }
    }

#pragma unroll
    for (int i = 0; i < 4; i++)
#pragma unroll
        for (int j = 0; j < 2; j++)
#pragma unroll
            for (int r = 0; r < 4; r++) {
                const int row = mBase + i * 16 + quad * 4 + r;
                const int col = nBase + wave * 32 + j * 16 + l16;
                Cf[(size_t)row * N + col] = acc[i][j][r] + bias[col];
            }
}

// ---------------- fused flash attention ----------------
// 512 thr = 8 waves = 4 qg x 2 kg; Bq=128, wave owns 32 q x 32 keys of each 64-key tile.
// grid (32,16): x=bh so linear id = bh + 32*qRow -> id%8 = bh%8: all 16 blocks of one (b,h)
// land on one XCD; 4 bh/XCD = 2MB K/V fits the 4MB L2 (T1; staging becomes L2-resident).
// P never touches LDS: after S^T-MFMA, exp2+pk2bf then permlane32/16 swaps rebuild the PV
// B-fragment in registers (T12). PV lags S by one tile (pfA/pfB named double-buffer).
// K dbuf 2x8KB, V 3-buf 3x8KB. smem ushort: [0,8192) K | [8192,20480) V | [20480,28672) Q-stage
// (region reused as f32 scratch in epilogue). 56KB -> 2 blocks/CU.
__global__ __launch_bounds__(512, 4)
void attn_flash(const ushort_t* __restrict__ qk, const ushort_t* __restrict__ vT,
                ushort_t* __restrict__ o) {
    __shared__ ushort_t smem[28672];

    const int tid = threadIdx.x;
    const int wave = tid >> 6, lane = tid & 63;
    const int quad = lane >> 4, l16 = lane & 15;
    const int qg = wave & 3, kg = wave >> 2;
    const int bh = blockIdx.x, b = bh >> 4, h = bh & 15;
    const size_t rowBase = (size_t)b * 2048;
    const int qCol = h * 64, kCol = 1024 + h * 64;
    const int qRow0 = blockIdx.y * 128;
    const int swz = l16 & 7;

    // staging geometry: 64 rows x 8 chunks per pass (512 thr = one full 64x64 tile), XOR swizzle
    const int sr = tid >> 3;                       // 0..63
    const int sc = ((tid & 7) ^ (sr & 7)) * 8;

    // ---- stage Q 128x64 (pre-scaled by SC) into [20480,28672), pull B-frags ----
#pragma unroll
    for (int cc = 0; cc < 2; cc++)
        gload_lds16(qk + (rowBase + qRow0 + cc * 64 + sr) * 2048 + qCol + sc,
                    smem + 20480 + cc * 4096 + wave * 512);
    __syncthreads();
    short8 qf[2][2];  // [qt][ks]: q = qg*32 + qt*16 + l16
#pragma unroll
    for (int qt = 0; qt < 2; qt++)
#pragma unroll
        for (int ks = 0; ks < 2; ks++)
            qf[qt][ks] = *(const short8*)(smem + 20480 + (qg * 32 + qt * 16 + l16) * 64 +
                                          (((ks * 4 + quad) ^ swz) * 8));

    short8 onesA;
#pragma unroll
    for (int i = 0; i < 8; i++) onesA[i] = (short)0x3F80;

    f32x4 oacc[4][2];  // [dt][qt]
    f32x4 lacc[2];     // [qt], entries replicate l
#pragma unroll
    for (int qt = 0; qt < 2; qt++) {
        lacc[qt] = (f32x4){0.f, 0.f, 0.f, 0.f};
#pragma unroll
        for (int dt = 0; dt < 4; dt++) oacc[dt][qt] = (f32x4){0.f, 0.f, 0.f, 0.f};
    }

    const ushort_t* kptr = qk + (rowBase + sr) * 2048 + kCol + sc;
    const ushort_t* vptr = vT + ((size_t)bh * 64 + sr) * 2048 + sc;

    f32x4 sacc[2][2];   // [mh][qt]
    short8 pfA[2], pfB[2];  // P frags, named double-buffer (rule #20: static indexing)

#define AT_STAGE(kbi, vbi, kt)                                                         \
    {                                                                                  \
        gload_lds16(kptr + (size_t)((kt) * 64) * 2048, smem + (kbi) * 4096 + wave * 512); \
        gload_lds16(vptr + (kt) * 64, smem + 8192 + (vbi) * 4096 + wave * 512);        \
    }

    // S^T = K·Q^T on 32 keys x 32 q: 4 reads feed 8 MFMA
#define S_BLOCK(cur)                                                                   \
    {                                                                                  \
        const ushort_t* lK = smem + (cur) * 4096;                                      \
        _Pragma("unroll") for (int mh = 0; mh < 2; mh++) {                             \
            const int krow = kg * 32 + mh * 16 + l16;                                  \
            const short8 k0 = *(const short8*)(lK + krow * 64 + ((quad ^ swz) * 8));   \
            const short8 k1 = *(const short8*)(lK + krow * 64 + (((4 + quad) ^ swz) * 8)); \
            __builtin_amdgcn_s_setprio(1);                                             \
            _Pragma("unroll") for (int qt = 0; qt < 2; qt++) {                         \
                f32x4 t = (f32x4){0.f, 0.f, 0.f, 0.f};                                 \
                t = __builtin_amdgcn_mfma_f32_16x16x32_bf16(k0, qf[qt][0], t, 0, 0, 0); \
                t = __builtin_amdgcn_mfma_f32_16x16x32_bf16(k1, qf[qt][1], t, 0, 0, 0); \
                sacc[mh][qt] = t;                                                      \
            }                                                                          \
            __builtin_amdgcn_s_setprio(0);                                             \
        }                                                                              \
    }

    // exp2 + pack + permlane: sacc -> PV B-frag in registers.
    // lane(quad,l16) holds S^T[k=mh*16+quad*4+r][q=l16]; frag needs P[k=quad*8+j][q=l16].
    // After plane32 then plane16 on (a,b): a = words for k-pairs {0,8,16,24}+quad-dependent,
    // i.e. a'' per quad = keys (quad*8, quad*8+1); b'' = keys (quad*8+4, quad*8+5).
#define EXPPK_BLOCK(pfdst)                                                             \
    _Pragma("unroll") for (int qt = 0; qt < 2; qt++) {                                 \
        uint32 a0 = pk2bf(EXP2F(sacc[0][qt][0]), EXP2F(sacc[0][qt][1]));               \
        uint32 a1 = pk2bf(EXP2F(sacc[0][qt][2]), EXP2F(sacc[0][qt][3]));               \
        uint32 b0 = pk2bf(EXP2F(sacc[1][qt][0]), EXP2F(sacc[1][qt][1]));               \
        uint32 b1 = pk2bf(EXP2F(sacc[1][qt][2]), EXP2F(sacc[1][qt][3]));               \
        plane32(a0, b0); plane16(a0, b0);                                              \
        plane32(a1, b1); plane16(a1, b1);                                              \
        union { uint32 u[4]; short8 s; } w_;                                           \
        w_.u[0] = a0; w_.u[1] = a1; w_.u[2] = b0; w_.u[3] = b1;                        \
        pfdst[qt] = w_.s;                                                              \
    }

    // P·V (+ones·P for l) for the LAGGED tile, P from registers
#define PV_BLOCK(vbi, pf)                                                              \
    {                                                                                  \
        const ushort_t* lV = smem + 8192 + (vbi) * 4096;                               \
        _Pragma("unroll") for (int qt = 0; qt < 2; qt++)                               \
            lacc[qt] = __builtin_amdgcn_mfma_f32_16x16x32_bf16(onesA, pf[qt], lacc[qt], 0, 0, 0); \
        __builtin_amdgcn_s_setprio(1);                                                 \
        _Pragma("unroll") for (int dt = 0; dt < 4; dt++) {                             \
            const short8 vf = *(const short8*)(lV + (dt * 16 + l16) * 64 +             \
                                               (((kg * 4 + quad) ^ swz) * 8));         \
            _Pragma("unroll") for (int qt = 0; qt < 2; qt++)                           \
                oacc[dt][qt] = __builtin_amdgcn_mfma_f32_16x16x32_bf16(vf, pf[qt], oacc[dt][qt], 0, 0, 0); \
        }                                                                              \
        __builtin_amdgcn_s_setprio(0);                                                 \
    }

    AT_STAGE(0, 0, 0);

    // iter 0 (peeled): no PV yet
    __syncthreads();
    AT_STAGE(1, 1, 1);
    S_BLOCK(0);
    EXPPK_BLOCK(pfA);   // tile 0 -> pfA

    // main loop, unrolled x2: odd kt reads pfA writes pfB; even kt reads pfB writes pfA.
    // vbuf[t%3] holds tile t; stage tile kt+1 while PV reads tile kt-1 ((kt+1)%3 != (kt-1)%3).
    int vs = 2;  // (kt+1)%3 at kt=1
    int vp = 0;  // (kt-1)%3 at kt=1
    for (int kt = 1; kt <= 29; kt += 2) {
        // ---- odd kt ----
        __syncthreads();              // tile kt staged
        AT_STAGE(0, vs, kt + 1);      // (kt+1)&1 == 0
        S_BLOCK(1);                   // kt&1 == 1
        PV_BLOCK(vp, pfA);            // tile kt-1
        EXPPK_BLOCK(pfB);             // tile kt
        vs = (vs == 2) ? 0 : vs + 1;
        vp = (vp == 2) ? 0 : vp + 1;
        // ---- even kt+1 ----
        __syncthreads();              // tile kt+1 staged
        AT_STAGE(1, vs, kt + 2);      // (kt+2)&1 == 1; kt+2 <= 31
        S_BLOCK(0);
        PV_BLOCK(vp, pfB);            // tile kt
        EXPPK_BLOCK(pfA);             // tile kt+1
        vs = (vs == 2) ? 0 : vs + 1;
        vp = (vp == 2) ? 0 : vp + 1;
    }

    // iter 31 (peeled): no stage. After loop: S/EXPPK done through tile 30 (in pfA),
    // PV done through tile 29; vbuf: tile30 -> 0, tile31 -> 1.
    __syncthreads();
    S_BLOCK(1);
    PV_BLOCK(0, pfA);   // tile 30
    EXPPK_BLOCK(pfB);   // tile 31
    PV_BLOCK(1, pfB);   // tile 31

    // ---- epilogue: combine the two key-halves through LDS, write O ----
    __syncthreads();  // all waves done with smem tiles
    float* red = (float*)smem;  // [0,8192) oacc f32, [8192,8320) l  (33.3KB < 56KB)
    if (kg == 1) {
#pragma unroll
        for (int qt = 0; qt < 2; qt++) {
            if (quad == 0) red[8192 + qg * 32 + qt * 16 + l16] = lacc[qt][0];
#pragma unroll
            for (int dt = 0; dt < 4; dt++)
                *(f32x4*)(red + (((qg * 4 + dt) * 2 + qt) * 64 + lane) * 4) = oacc[dt][qt];
        }
    }
    __syncthreads();
    if (kg == 0) {
        float linv[2];
#pragma unroll
        for (int qt = 0; qt < 2; qt++)
            linv[qt] = 1.0f / (lacc[qt][0] + red[8192 + qg * 32 + qt * 16 + l16]);
#pragma unroll
        for (int qt = 0; qt < 2; qt++) {
            const size_t row = rowBase + qRow0 + qg * 32 + qt * 16 + l16;
#pragma unroll
            for (int dt = 0; dt < 4; dt++) {
                const f32x4 r = *(const f32x4*)(red + (((qg * 4 + dt) * 2 + qt) * 64 + lane) * 4);
                uint2 pk;
                pk.x = pk2bf((oacc[dt][qt][0] + r[0]) * linv[qt],
                             (oacc[dt][qt][1] + r[1]) * linv[qt]);
                pk.y = pk2bf((oacc[dt][qt][2] + r[2]) * linv[qt],
                             (oacc[dt][qt][3] + r[3]) * linv[qt]);
                *(uint2*)(o + row * 1024 + h * 64 + dt * 16 + quad * 4) = pk;
            }
        }
    }
}

extern "C" void kernel_launch(void* const* d_in, const int* in_sizes, int n_in,
                              void* d_out, int out_size, void* d_ws, size_t ws_size,
                              hipStream_t stream) {
    const float* x    = (const float*)d_in[0];
    const float* Wqkv = (const float*)d_in[1];
    const float* Wout = (const float*)d_in[2];
    const float* bout = (const float*)d_in[3];
    float* out = (float*)d_out;

    ushort_t* xb    = (ushort_t*)d_ws;                    // 4096*1024
    ushort_t* wqkvb = xb + (size_t)4096 * 1024;           // 3072*1024
    ushort_t* woutb = wqkvb + (size_t)3072 * 1024;        // 1024*1024
    ushort_t* qkb   = woutb + (size_t)1024 * 1024;        // 4096*2048 (Q*SC, K)
    ushort_t* vTb   = qkb + (size_t)4096 * 2048;          // 32*64*2048 (V^T)
    ushort_t* ob    = xb;                                 // alias: x dead after GEMM1

    const float SC = 0.125f * 1.44269504089f;  // SCALE * log2(e)

    cvt_all<<<8192, 256, 0, stream>>>(x, xb, Wqkv, wqkvb, Wout, woutb);
    gemm_qkv<<<dim3(24, 32), 256, 0, stream>>>(xb, wqkvb, qkb, vTb, 4096, 3072, 1024, 2048, SC);
    // grid (32,16): x=bh -> linear id = bh + 32*qRow -> XCD = bh%8 (K/V L2-resident per XCD)
    attn_flash<<<dim3(32, 16), 512, 0, stream>>>(qkb, vTb, ob);
    gemm_out<<<dim3(8, 64), 256, 0, stream>>>(ob, woutb, out, bout, 4096, 1024, 1024);
}